// Round 1
// baseline (459.875 us; speedup 1.0000x reference)
//
#include <hip/hip_runtime.h>

// Temporally-blocked Jacobi, register-resident + packed-fp32: 5 x 10 steps.
// v2 — occupancy push. LDS cut 33792B -> 17408B so 8 blocks/CU (32 waves/CU):
//  * center 4x4 patch staged straight into registers via coalesced float2
//    loads (no full-tile LDS buffer, no LDS round-trip for the center)
//  * LDS holds ONLY the 32 exchanged boundary rows (+2 dummy slots),
//    double-buffered: slot(T_c)=2c+1 (row 4c), slot(B_c)=2c+2 (row 4c+5).
//    Chunk c's per-step exchange writes rows R0 (=B_{c-1} -> slot 2c) and
//    R0+3 (=T_{c+1} -> slot 2c+3); executed at s=0 too, this populates all
//    interior step-0 halos for free. Only tile rows 0 and 65 (slots 1, 32)
//    need explicit staging; they go stale after step 0, contaminating only
//    rows outside the kept 10..53 window (same tolerance as v1).
//  * exactly one __syncthreads per step (10 total, was 11).

#define NX 1024
#define BATCH 16
#define TSTEPS 10
#define OUT 44
#define HI 53            // last valid data row/col
#define PITCH 64
#define SLOTS 34         // slot 0 and 33 are write-dummies for chunks 0/15

typedef float v2f __attribute__((ext_vector_type(2)));

__device__ __forceinline__ int reflect_idx(int i) {
    i = (i < 0) ? -i : i;
    return (i > NX - 1) ? 2 * (NX - 1) - i : i;
}

// lane g gets lane g-1's value within each 16-lane DPP row (edges keep own: garbage-allowed)
__device__ __forceinline__ float dpp_shr1(float x) {
    int v = __float_as_int(x);
    return __int_as_float(__builtin_amdgcn_update_dpp(v, v, 0x111, 0xF, 0xF, false));
}
__device__ __forceinline__ float dpp_shl1(float x) {
    int v = __float_as_int(x);
    return __int_as_float(__builtin_amdgcn_update_dpp(v, v, 0x101, 0xF, 0xF, false));
}

__device__ __forceinline__ v2f pk_add(v2f a, v2f b) {
    v2f d; asm("v_pk_add_f32 %0, %1, %2" : "=v"(d) : "v"(a), "v"(b)); return d;
}
__device__ __forceinline__ v2f pk_fma(v2f a, v2f b, v2f c) {
    v2f d; asm("v_pk_fma_f32 %0, %1, %2, %3" : "=v"(d) : "v"(a), "v"(b), "v"(c)); return d;
}

__global__ __launch_bounds__(256, 8) void jacobi_fused(const float* __restrict__ src,
                                                       const float* __restrict__ layout,
                                                       float* __restrict__ dst) {
    __shared__ float buf[2][SLOTS * PITCH];

    const float COF = (float)(0.25 * (0.1 / 1023.0) * (0.1 / 1023.0));

    const int tid = threadIdx.x;
    const int g = tid & 15;                      // col group: data cols 4g..4g+3
    const int c = tid >> 4;                      // row chunk: rows 1+4c..4+4c
    const int gr0 = blockIdx.y * OUT - TSTEPS;
    const int gc0 = blockIdx.x * OUT - TSTEPS;
    const int base = blockIdx.z * NX * NX;
    const int R0 = 1 + 4 * c;
    const int C0 = 4 * g;

    v2f E[4], O[4], fE[4], fO[4];

    const bool interior = (blockIdx.x >= 1) && (blockIdx.x <= 22) &&
                          (blockIdx.y >= 1) && (blockIdx.y <= 22);

    if (interior) {
        // ---- fast staging: center patch + f straight to registers ----
        const float* sb = src + base + (gr0 + R0) * NX + gc0 + C0;
        const float* lb = layout + base + (gr0 + R0) * NX + gc0 + C0;
#pragma unroll
        for (int i = 0; i < 4; ++i) {
            v2f a = *(const v2f*)(sb + i * NX);        // cols C0, C0+1 (8B-aligned)
            v2f b = *(const v2f*)(sb + i * NX + 2);    // cols C0+2, C0+3
            E[i] = (v2f){a.x, b.x};
            O[i] = (v2f){a.y, b.y};
        }
#pragma unroll
        for (int i = 0; i < 4; ++i) {
            v2f a = *(const v2f*)(lb + i * NX);
            v2f b = *(const v2f*)(lb + i * NX + 2);
            fE[i] = (v2f){COF * a.x, COF * b.x};
            fO[i] = (v2f){COF * a.y, COF * b.y};
        }
        // global halo rows 0 and 65 -> slots 1 and 32 (bit-swapped E/O layout)
        if (tid < 128) {
            const int rsel = tid >> 6;                 // 0: row 0, 1: row 65
            const int q2 = tid & 31;                   // col pair 2q2, 2q2+1
            const int slot = rsel ? 32 : 1;
            v2f v = *(const v2f*)(src + base + (gr0 + (rsel ? 65 : 0)) * NX + gc0 + 2 * q2);
            const int lo = 4 * (q2 >> 1) + (q2 & 1);
            buf[0][slot * PITCH + lo]     = v.x;
            buf[0][slot * PITCH + lo + 2] = v.y;
        }
    } else {
        // ---- slow staging: reflect-mapped scalar loads ----
#pragma unroll
        for (int i = 0; i < 4; ++i) {
            const int grr = reflect_idx(gr0 + R0 + i);
            const float* sr = src + base + grr * NX;
            const float* lr = layout + base + grr * NX;
            const int c0 = reflect_idx(gc0 + C0);
            const int c1 = reflect_idx(gc0 + C0 + 1);
            const int c2 = reflect_idx(gc0 + C0 + 2);
            const int c3 = reflect_idx(gc0 + C0 + 3);
            E[i]  = (v2f){sr[c0], sr[c2]};
            O[i]  = (v2f){sr[c1], sr[c3]};
            fE[i] = (v2f){COF * lr[c0], COF * lr[c2]};
            fO[i] = (v2f){COF * lr[c1], COF * lr[c3]};
        }
        if (tid < 128) {
            const int rsel = tid >> 6;
            const int q = tid & 63;
            const int slot = rsel ? 32 : 1;
            const int grr = reflect_idx(gr0 + (rsel ? 65 : 0));
            const int lo = (q & ~3) | ((q & 1) << 1) | ((q >> 1) & 1);   // swap low 2 bits
            buf[0][slot * PITCH + lo] = src[base + grr * NX + reflect_idx(gc0 + q)];
        }
    }

    const v2f qq = (v2f){0.25f, 0.25f};
    const int wT = (2 * c) * PITCH + C0;         // row R0   = B_{c-1}
    const int wB = (2 * c + 3) * PITCH + C0;     // row R0+3 = T_{c+1}
    const int rT = (2 * c + 1) * PITCH + C0;     // top halo (row 4c)
    const int rB = (2 * c + 2) * PITCH + C0;     // bottom halo (row 4c+5)

    // ---- 10 fused steps; one barrier per step ----
#pragma unroll
    for (int s = 0; s < TSTEPS; ++s) {
        float* bb = buf[s & 1];
        *(float4*)&bb[wT] = make_float4(E[0].x, E[0].y, O[0].x, O[0].y);
        *(float4*)&bb[wB] = make_float4(E[3].x, E[3].y, O[3].x, O[3].y);
        __syncthreads();
        const float4 t  = *(const float4*)&bb[rT];
        const float4 bo = *(const float4*)&bb[rB];
        v2f upE = (v2f){t.x, t.y};
        v2f upO = (v2f){t.z, t.w};
        const v2f botE = (v2f){bo.x, bo.y};
        const v2f botO = (v2f){bo.z, bo.w};
#pragma unroll
        for (int i = 0; i < 4; ++i) {
            v2f dnE = (i == 3) ? botE : E[i + 1];
            v2f dnO = (i == 3) ? botO : O[i + 1];
            v2f vE = pk_add(upE, dnE);
            v2f vO = pk_add(upO, dnO);
            v2f P; P.x = dpp_shr1(O[i].y); P.y = O[i].x;   // (lf, c1)
            v2f Q; Q.x = E[i].y; Q.y = dpp_shl1(E[i].x);   // (c2, rt)
            v2f hE = pk_add(P, O[i]);                      // (lf+c1, c1+c3)
            v2f hO = pk_add(E[i], Q);                      // (c0+c2, c2+rt)
            upE = E[i]; upO = O[i];                        // old center = next row's up
            E[i] = pk_fma(pk_add(vE, hE), qq, fE[i]);
            O[i] = pk_fma(pk_add(vO, hO), qq, fO[i]);
        }
    }

    // ---- store central 44x44 from registers ----
#pragma unroll
    for (int i = 0; i < 4; ++i) {
        const int br = R0 + i;
        const bool rowok = (br >= TSTEPS) && (br <= HI) && (gr0 + br < NX);
        float v[4] = {E[i].x, O[i].x, E[i].y, O[i].y};     // c0,c1,c2,c3
#pragma unroll
        for (int k = 0; k < 4; ++k) {
            const int dcol = C0 + k;
            if (rowok && dcol >= TSTEPS && dcol <= HI && (gc0 + dcol) < NX)
                dst[base + (gr0 + br) * NX + (gc0 + dcol)] = v[k];
        }
    }
}

extern "C" void kernel_launch(void* const* d_in, const int* in_sizes, int n_in,
                              void* d_out, int out_size, void* d_ws, size_t ws_size,
                              hipStream_t stream) {
    const float* layout = (const float*)d_in[0];
    const float* heat   = (const float*)d_in[1];
    float* out = (float*)d_out;
    float* ws  = (float*)d_ws;

    dim3 grid((NX + OUT - 1) / OUT, (NX + OUT - 1) / OUT, BATCH);  // 24 x 24 x 16
    dim3 block(256);

    jacobi_fused<<<grid, block, 0, stream>>>(heat, layout, out);
    jacobi_fused<<<grid, block, 0, stream>>>(out,  layout, ws);
    jacobi_fused<<<grid, block, 0, stream>>>(ws,   layout, out);
    jacobi_fused<<<grid, block, 0, stream>>>(out,  layout, ws);
    jacobi_fused<<<grid, block, 0, stream>>>(ws,   layout, out);
}